// Round 5
// baseline (297.072 us; speedup 1.0000x reference)
//
#include <hip/hip_runtime.h>

typedef __attribute__((ext_vector_type(8))) short bhalf8;
typedef __attribute__((ext_vector_type(4))) float floatx4;

#define ALPHA_LR 0.2f

__device__ __forceinline__ unsigned short f2bf(float f) {
  union { float f; unsigned int u; } v; v.f = f;
  unsigned int r = v.u + 0x7fffu + ((v.u >> 16) & 1u);
  return (unsigned short)(r >> 16);
}
__device__ __forceinline__ float bf2f(unsigned short u) {
  union { unsigned int u; float f; } v; v.u = ((unsigned int)u) << 16;
  return v.f;
}
// async global->LDS, 16B per lane; LDS dest is wave-uniform base + lane*16
__device__ __forceinline__ void gld16(const void* g, void* l) {
  __builtin_amdgcn_global_load_lds((const __attribute__((address_space(1))) unsigned int*)g,
                                   (__attribute__((address_space(3))) unsigned int*)l,
                                   16, 0, 0);
}

// ---------------------------------------------------------------------------
// k0w: W [k][n] fp32 -> WT_hi/WT_lo bf16, k-tiled layout [ks=8][n=256][k'=32].
// Also re-initializes s2maxEnc[8] (ws is re-poisoned before every call).
// ---------------------------------------------------------------------------
__global__ void k0w_split(const float* __restrict__ W,
                          unsigned short* __restrict__ WThi,
                          unsigned short* __restrict__ WTlo,
                          unsigned int* __restrict__ s2maxEnc) {
  __shared__ float s[16][17];
  const int tx = threadIdx.x, ty = threadIdx.y;
  if (blockIdx.x == 0 && blockIdx.y == 0 && ty == 0 && tx < 8) s2maxEnc[tx] = 0u;
  const int n0 = blockIdx.x * 16, k0 = blockIdx.y * 16;
  s[ty][tx] = W[(k0 + ty) * 256 + n0 + tx];
  __syncthreads();
  float v = s[tx][ty];  // = W[k0+tx][n0+ty]
  const int k = k0 + tx, n = n0 + ty;
  unsigned short hi = f2bf(v);
  unsigned short lo = f2bf(v - bf2f(hi));
  const int idx = (k >> 5) * 8192 + n * 32 + (k & 31);
  WThi[idx] = hi;
  WTlo[idx] = lo;
}

// ---------------------------------------------------------------------------
// k2_pack: adj int32 0/1 (134 MB) -> bitmask (4 MB). Wave reads 64 consecutive
// ints (256 B coalesced), __ballot(v>0) -> uint64 (bit l == j-offset l), lane 0
// writes. 4-deep ILP so 4 loads/wave in flight; 8192 waves = full occupancy.
// HBM-floor ~22 us. Viewed as uint32: mask32[row*64 + jt] = bits j=jt*32..+31.
// ---------------------------------------------------------------------------
__global__ __launch_bounds__(256) void k2_pack(const int* __restrict__ adj,
                                               unsigned long long* __restrict__ mask) {
  const int wave = threadIdx.x >> 6, lane = threadIdx.x & 63;
  const long wid = (long)blockIdx.x * 4 + wave;  // 0..8191
  const long u0 = wid * 64;                      // first uint64 this wave packs
  const int* base = adj + u0 * 64 + lane;
#pragma unroll
  for (int it = 0; it < 64; it += 4) {
    int v0 = base[(it + 0) * 64];
    int v1 = base[(it + 1) * 64];
    int v2 = base[(it + 2) * 64];
    int v3 = base[(it + 3) * 64];
    unsigned long long m0 = __ballot(v0 > 0);
    unsigned long long m1 = __ballot(v1 > 0);
    unsigned long long m2 = __ballot(v2 > 0);
    unsigned long long m3 = __ballot(v3 > 0);
    if (lane == 0) {
      mask[u0 + it + 0] = m0;
      mask[u0 + it + 1] = m1;
      mask[u0 + it + 2] = m2;
      mask[u0 + it + 3] = m3;
    }
  }
}

// ---------------------------------------------------------------------------
// k1: Wh = h @ W via split-bf16 MFMA (hi*hi + hi*lo + lo*hi), h split in-kernel.
// Writes WhPack bf16 [B][jt=64][f=256][j'=32], s1/s2 (fp32 dots with a), and
// per-batch encoded atomicMax of s2 (for the k3 softmax bound).
// ---------------------------------------------------------------------------
__global__ __launch_bounds__(512, 2) void k1_mfma(const float* __restrict__ h,
                                                  const unsigned short* __restrict__ Bhi_g,
                                                  const unsigned short* __restrict__ Blo_g,
                                                  const float* __restrict__ a_g,
                                                  unsigned short* __restrict__ WhPack,
                                                  float* __restrict__ s1,
                                                  float* __restrict__ s2,
                                                  unsigned int* __restrict__ s2maxEnc) {
  __shared__ unsigned short Ah[64 * 264], Al[64 * 264];  // 33 KB each
  __shared__ unsigned short Bh[2][8192], Bl[2][8192];    // 16 KB per buffer
  __shared__ float s1red[64], s2red[64];
  const int t = threadIdx.x;
  const long r0 = (long)blockIdx.x * 64;
  const int wave = t >> 6, lane = t & 63;

  if (t < 64) { s1red[t] = 0.f; s2red[t] = 0.f; }

#pragma unroll
  for (int rep = 0; rep < 2; rep++) {
    const int off = wave * 1024 + rep * 512;
    gld16(Bhi_g + off + lane * 8, &Bh[0][off]);
    gld16(Blo_g + off + lane * 8, &Bl[0][off]);
  }

#pragma unroll
  for (int q = 0; q < 8; q++) {
    int idx = q * 512 + t;
    int row = idx >> 6, c4 = idx & 63;
    float4 x = *(const float4*)(h + (r0 + row) * 256 + c4 * 4);
    float xs[4] = {x.x, x.y, x.z, x.w};
    unsigned short hs[4], ls[4];
#pragma unroll
    for (int qq = 0; qq < 4; qq++) {
      hs[qq] = f2bf(xs[qq]);
      ls[qq] = f2bf(xs[qq] - bf2f(hs[qq]));
    }
    *(ushort4*)&Ah[row * 264 + c4 * 4] = (ushort4){hs[0], hs[1], hs[2], hs[3]};
    *(ushort4*)&Al[row * 264 + c4 * 4] = (ushort4){ls[0], ls[1], ls[2], ls[3]};
  }
  __syncthreads();

  const int wm = wave >> 2, wn = wave & 3;
  const int lhi = lane >> 4, llo = lane & 15;

  floatx4 acc[2][4];
#pragma unroll
  for (int mt = 0; mt < 2; mt++)
#pragma unroll
    for (int nt = 0; nt < 4; nt++) acc[mt][nt] = (floatx4){0.f, 0.f, 0.f, 0.f};

  for (int ks = 0; ks < 8; ks++) {
    const int cur = ks & 1, nxt = cur ^ 1, ksn = (ks + 1) & 7;
#pragma unroll
    for (int rep = 0; rep < 2; rep++) {
      const int off = wave * 1024 + rep * 512;
      gld16(Bhi_g + ksn * 8192 + off + lane * 8, &Bh[nxt][off]);
      gld16(Blo_g + ksn * 8192 + off + lane * 8, &Bl[nxt][off]);
    }

    const int k0 = ks * 32;
    bhalf8 ah[2], al[2], bh[4], bl[4];
#pragma unroll
    for (int mt = 0; mt < 2; mt++) {
      int ro = (wm * 32 + mt * 16 + llo) * 264 + k0 + lhi * 8;
      ah[mt] = *(const bhalf8*)&Ah[ro];
      al[mt] = *(const bhalf8*)&Al[ro];
    }
#pragma unroll
    for (int nt = 0; nt < 4; nt++) {
      int ro = (wn * 64 + nt * 16 + llo) * 32 + lhi * 8;
      bh[nt] = *(const bhalf8*)&Bh[cur][ro];
      bl[nt] = *(const bhalf8*)&Bl[cur][ro];
    }
#pragma unroll
    for (int mt = 0; mt < 2; mt++)
#pragma unroll
      for (int nt = 0; nt < 4; nt++) {
        acc[mt][nt] = __builtin_amdgcn_mfma_f32_16x16x32_bf16(ah[mt], bh[nt], acc[mt][nt], 0, 0, 0);
        acc[mt][nt] = __builtin_amdgcn_mfma_f32_16x16x32_bf16(ah[mt], bl[nt], acc[mt][nt], 0, 0, 0);
        acc[mt][nt] = __builtin_amdgcn_mfma_f32_16x16x32_bf16(al[mt], bh[nt], acc[mt][nt], 0, 0, 0);
      }
    __syncthreads();
  }

  float a1v[4], a2v[4];
#pragma unroll
  for (int nt = 0; nt < 4; nt++) {
    int f = wn * 64 + nt * 16 + llo;
    a1v[nt] = a_g[f];
    a2v[nt] = a_g[256 + f];
  }

  const int b = (int)(r0 >> 11);
  const int jt_base = (int)((r0 & 2047) >> 5);

#pragma unroll
  for (int mt = 0; mt < 2; mt++) {
    float p1[4], p2[4];
#pragma unroll
    for (int reg = 0; reg < 4; reg++) {
      p1[reg] = acc[mt][0][reg] * a1v[0] + acc[mt][1][reg] * a1v[1] +
                acc[mt][2][reg] * a1v[2] + acc[mt][3][reg] * a1v[3];
      p2[reg] = acc[mt][0][reg] * a2v[0] + acc[mt][1][reg] * a2v[1] +
                acc[mt][2][reg] * a2v[2] + acc[mt][3][reg] * a2v[3];
    }
#pragma unroll
    for (int off = 1; off < 16; off <<= 1) {
#pragma unroll
      for (int reg = 0; reg < 4; reg++) {
        p1[reg] += __shfl_xor(p1[reg], off);
        p2[reg] += __shfl_xor(p2[reg], off);
      }
    }
    if (llo == 0) {
#pragma unroll
      for (int reg = 0; reg < 4; reg++) {
        int il = wm * 32 + mt * 16 + lhi * 4 + reg;
        atomicAdd(&s1red[il], p1[reg]);
        atomicAdd(&s2red[il], p2[reg]);
      }
    }
#pragma unroll
    for (int nt = 0; nt < 4; nt++) {
      int f = wn * 64 + nt * 16 + llo;
      int jt = jt_base + wm;
      ushort4 pk = (ushort4){f2bf(acc[mt][nt][0]), f2bf(acc[mt][nt][1]),
                             f2bf(acc[mt][nt][2]), f2bf(acc[mt][nt][3])};
      *(ushort4*)&WhPack[((long)((b * 64 + jt) * 256 + f)) * 32 + mt * 16 + lhi * 4] = pk;
    }
  }

  __syncthreads();
  if (t < 64) {
    s1[r0 + t] = s1red[t];
    s2[r0 + t] = s2red[t];
    // per-batch max(s2): 64-lane reduce + one encoded atomicMax per block
    float v = s2red[t];
#pragma unroll
    for (int o = 32; o; o >>= 1) v = fmaxf(v, __shfl_xor(v, o));
    if (t == 0) {
      unsigned int u = __float_as_uint(v);
      unsigned int key = (u & 0x80000000u) ? ~u : (u | 0x80000000u);
      atomicMax(s2maxEnc + b, key);
    }
  }
}

// ---------------------------------------------------------------------------
// K3 v6 (bitmask adj): v5's barrier-free in-register-P structure, but adj is
// consumed as a packed bitmask (k2_pack): per lane per jt, TWO 4-B uint loads
// (rows llo, llo+16; L2-resident, 0.5 MB/batch on own XCD) replace 128 B of
// int32 HBM stream. All k3 operands (Wh, s2, mask) are now L2-resident ->
// the depth-1 pinned pipeline (~300 cyc to hide) is covered by one compute
// region (~500 cyc of exp+MFMA). ZERO LDS, ZERO barriers.
// grid 256 x 512 thr; XCD-affine b = lin&7.
// ---------------------------------------------------------------------------
__global__ __launch_bounds__(512, 2) void k3_attn(const unsigned short* __restrict__ WhPack,
                                                  const unsigned int* __restrict__ mask32,
                                                  const float* __restrict__ s1g,
                                                  const float* __restrict__ s2g,
                                                  const unsigned int* __restrict__ s2maxEnc,
                                                  float* __restrict__ out) {
  const int t = threadIdx.x;
  const int lin = blockIdx.x;
  const int b = lin & 7;  // XCD-affine: round-robin dispatch -> XCD = lin%8
  const int ig = lin >> 3;
  const int wave = t >> 6, lane = t & 63;
  const int rg = wave >> 2, fg = wave & 3;
  const int i0 = ig * 64 + rg * 32;
  const long gr0 = (long)b * 2048 + i0;
  const int llo = lane & 15, lhi = lane >> 4;
  const int sh = lhi * 8;  // bit shift for this lane's j-subchunk

  const unsigned int ek = s2maxEnc[b];
  const float s2max = (ek & 0x80000000u) ? __uint_as_float(ek & 0x7fffffffu)
                                         : __uint_as_float(~ek);
  float s1i[2], Mi[2];
#pragma unroll
  for (int mt = 0; mt < 2; mt++) {
    s1i[mt] = s1g[gr0 + mt * 16 + llo];
    float xm = s1i[mt] + s2max;
    Mi[mt] = fmaxf(xm, ALPHA_LR * xm);
  }

  const float* s2p = s2g + (long)b * 2048 + lhi * 8;  // + jt*32
  // bitmask rows: mask32[row*64 + jt], bits j = jt*32 .. +31
  const unsigned int* mp0 = mask32 + (gr0 + llo) * 64;
  const unsigned int* mp1 = mp0 + 16 * 64;
  const unsigned short* wb =
      WhPack + (long)b * 524288 + (long)((fg * 64 + llo) * 32 + lhi * 8);

  // ---- prologue: jt=0 operands ----
  unsigned int cm0 = mp0[0], cm1 = mp1[0];
  float4 s2A = *(const float4*)s2p;
  float4 s2B = *(const float4*)(s2p + 4);
  bhalf8 bF[4];
#pragma unroll
  for (int nt = 0; nt < 4; nt++) bF[nt] = *(const bhalf8*)(wb + nt * 512);

  floatx4 acc[2][4];
#pragma unroll
  for (int mt = 0; mt < 2; mt++)
#pragma unroll
    for (int nt = 0; nt < 4; nt++) acc[mt][nt] = (floatx4){0.f, 0.f, 0.f, 0.f};
  float ls0 = 0.f, ls1 = 0.f;

#pragma unroll 2
  for (int jt = 0; jt < 64; jt++) {
    const int jn = (jt < 63) ? jt + 1 : 63;

    // ---- ISSUE block: next-iteration loads, pinned above compute ----
    bhalf8 bFn[4];
#pragma unroll
    for (int nt = 0; nt < 4; nt++)
      bFn[nt] = *(const bhalf8*)(wb + (long)jn * 8192 + nt * 512);
    float4 s2nA = *(const float4*)(s2p + jn * 32);
    float4 s2nB = *(const float4*)(s2p + jn * 32 + 4);
    unsigned int nm0 = mp0[jn], nm1 = mp1[jn];

    __builtin_amdgcn_sched_barrier(0);  // loads may NOT sink below this point

    // ---- COMPUTE block: P for current jt, fully in-register ----
    bhalf8 pa[2];
#pragma unroll
    for (int mt = 0; mt < 2; mt++) {
      const float s1v = s1i[mt], miv = Mi[mt];
      const unsigned int mb = ((mt ? cm1 : cm0) >> sh) & 0xffu;
      float xs[8] = {s2A.x, s2A.y, s2A.z, s2A.w, s2B.x, s2B.y, s2B.z, s2B.w};
      float e[8];
      float lsm = 0.f;
#pragma unroll
      for (int q = 0; q < 8; q++) {
        float x = s1v + xs[q];
        float lk = fmaxf(x, ALPHA_LR * x);
        float ee = __expf(lk - miv);
        ee = (mb & (1u << q)) ? ee : 0.f;
        lsm += ee;
        e[q] = ee;
      }
      if (mt) ls1 += lsm; else ls0 += lsm;
      union { unsigned int u[4]; bhalf8 v; } pk;
#pragma unroll
      for (int q = 0; q < 4; q++)
        asm("v_cvt_pk_bf16_f32 %0, %1, %2" : "=v"(pk.u[q]) : "v"(e[2 * q]), "v"(e[2 * q + 1]));
      pa[mt] = pk.v;
    }

#pragma unroll
    for (int mt = 0; mt < 2; mt++)
#pragma unroll
      for (int nt = 0; nt < 4; nt++)
        acc[mt][nt] = __builtin_amdgcn_mfma_f32_16x16x32_bf16(mt ? pa[1] : pa[0],
                                                              bF[nt], acc[mt][nt], 0, 0, 0);

    // ---- rotate pipelined registers ----
    cm0 = nm0; cm1 = nm1;
    s2A = s2nA; s2B = s2nB;
#pragma unroll
    for (int nt = 0; nt < 4; nt++) bF[nt] = bFn[nt];
  }

  // denominator: rows mt*16+llo; partial over lhi j-slices -> reduce across lhi
  ls0 += __shfl_xor(ls0, 16); ls0 += __shfl_xor(ls0, 32);
  ls1 += __shfl_xor(ls1, 16); ls1 += __shfl_xor(ls1, 32);
  float inv0 = 1.f / fmaxf(ls0, 1e-35f);
  float inv1 = 1.f / fmaxf(ls1, 1e-35f);

  // epilogue: normalize, ELU, store. C/D: row = lhi*4+reg, col = llo.
  // inv for row r lives in lanes with llo==r -> fetch via shfl from lane r.
#pragma unroll
  for (int mt = 0; mt < 2; mt++) {
#pragma unroll
    for (int reg = 0; reg < 4; reg++) {
      const int rloc = lhi * 4 + reg;
      float iv = __shfl(mt ? inv1 : inv0, rloc);
      const long orow = (gr0 + mt * 16 + rloc) * 256 + fg * 64 + llo;
#pragma unroll
      for (int nt = 0; nt < 4; nt++) {
        float v = acc[mt][nt][reg] * iv;
        v = v > 0.f ? v : expm1f(v);
        out[orow + nt * 16] = v;
      }
    }
  }
}

// ---------------------------------------------------------------------------
extern "C" void kernel_launch(void* const* d_in, const int* in_sizes, int n_in,
                              void* d_out, int out_size, void* d_ws, size_t ws_size,
                              hipStream_t stream) {
  const float* h = (const float*)d_in[0];
  const int* adj = (const int*)d_in[1];
  const float* W = (const float*)d_in[2];
  const float* a = (const float*)d_in[3];
  float* out = (float*)d_out;

  char* ws = (char*)d_ws;
  unsigned short* WhPack = (unsigned short*)ws;            //  8,388,608 B
  unsigned short* WThi = (unsigned short*)(ws + 8388608);  //    131,072 B
  unsigned short* WTlo = (unsigned short*)(ws + 8519680);  //    131,072 B
  float* s1 = (float*)(ws + 8650752);                      //     65,536 B
  float* s2 = (float*)(ws + 8716288);                      //     65,536 B
  unsigned int* s2maxEnc = (unsigned int*)(ws + 8781824);  //         32 B
  unsigned long long* adjMask = (unsigned long long*)(ws + 8912896);  // 4,194,304 B

  hipLaunchKernelGGL(k0w_split, dim3(16, 16), dim3(16, 16), 0, stream, W, WThi, WTlo, s2maxEnc);
  hipLaunchKernelGGL(k1_mfma, dim3(256), dim3(512), 0, stream, h, WThi, WTlo, a,
                     WhPack, s1, s2, s2maxEnc);
  hipLaunchKernelGGL(k2_pack, dim3(2048), dim3(256), 0, stream, adj, adjMask);
  hipLaunchKernelGGL(k3_attn, dim3(256), dim3(512), 0, stream, WhPack,
                     (const unsigned int*)adjMask, s1, s2, s2maxEnc, out);
}

// Round 6
// 295.154 us; speedup vs baseline: 1.0065x; 1.0065x over previous
//
#include <hip/hip_runtime.h>

typedef __attribute__((ext_vector_type(8))) short bhalf8;
typedef __attribute__((ext_vector_type(4))) float floatx4;

#define ALPHA_LR 0.2f

__device__ __forceinline__ unsigned short f2bf(float f) {
  union { float f; unsigned int u; } v; v.f = f;
  unsigned int r = v.u + 0x7fffu + ((v.u >> 16) & 1u);
  return (unsigned short)(r >> 16);
}
__device__ __forceinline__ float bf2f(unsigned short u) {
  union { unsigned int u; float f; } v; v.u = ((unsigned int)u) << 16;
  return v.f;
}
// async global->LDS, 16B per lane; LDS dest is wave-uniform base + lane*16
__device__ __forceinline__ void gld16(const void* g, void* l) {
  __builtin_amdgcn_global_load_lds((const __attribute__((address_space(1))) unsigned int*)g,
                                   (__attribute__((address_space(3))) unsigned int*)l,
                                   16, 0, 0);
}

// ---------------------------------------------------------------------------
// k0w: W [k][n] fp32 -> WT_hi/WT_lo bf16, k-tiled layout [ks=8][n=256][k'=32].
// Also re-initializes s2maxEnc[8] (ws is re-poisoned before every call).
// ---------------------------------------------------------------------------
__global__ void k0w_split(const float* __restrict__ W,
                          unsigned short* __restrict__ WThi,
                          unsigned short* __restrict__ WTlo,
                          unsigned int* __restrict__ s2maxEnc) {
  __shared__ float s[16][17];
  const int tx = threadIdx.x, ty = threadIdx.y;
  if (blockIdx.x == 0 && blockIdx.y == 0 && ty == 0 && tx < 8) s2maxEnc[tx] = 0u;
  const int n0 = blockIdx.x * 16, k0 = blockIdx.y * 16;
  s[ty][tx] = W[(k0 + ty) * 256 + n0 + tx];
  __syncthreads();
  float v = s[tx][ty];  // = W[k0+tx][n0+ty]
  const int k = k0 + tx, n = n0 + ty;
  unsigned short hi = f2bf(v);
  unsigned short lo = f2bf(v - bf2f(hi));
  const int idx = (k >> 5) * 8192 + n * 32 + (k & 31);
  WThi[idx] = hi;
  WTlo[idx] = lo;
}

// ---------------------------------------------------------------------------
// k2_pack: adj int32 0/1 (134 MB) -> bitmask (4 MB). Wave reads 64 consecutive
// ints (256 B coalesced), __ballot(v>0) -> uint64, lane 0 writes. HBM-floor
// ~22 us. Viewed as uint32: mask32[row*64 + jt] = bits j=jt*32..+31.
// ---------------------------------------------------------------------------
__global__ __launch_bounds__(256) void k2_pack(const int* __restrict__ adj,
                                               unsigned long long* __restrict__ mask) {
  const int wave = threadIdx.x >> 6, lane = threadIdx.x & 63;
  const long wid = (long)blockIdx.x * 4 + wave;  // 0..8191
  const long u0 = wid * 64;                      // first uint64 this wave packs
  const int* base = adj + u0 * 64 + lane;
#pragma unroll
  for (int it = 0; it < 64; it += 4) {
    int v0 = base[(it + 0) * 64];
    int v1 = base[(it + 1) * 64];
    int v2 = base[(it + 2) * 64];
    int v3 = base[(it + 3) * 64];
    unsigned long long m0 = __ballot(v0 > 0);
    unsigned long long m1 = __ballot(v1 > 0);
    unsigned long long m2 = __ballot(v2 > 0);
    unsigned long long m3 = __ballot(v3 > 0);
    if (lane == 0) {
      mask[u0 + it + 0] = m0;
      mask[u0 + it + 1] = m1;
      mask[u0 + it + 2] = m2;
      mask[u0 + it + 3] = m3;
    }
  }
}

// ---------------------------------------------------------------------------
// k1: Wh = h @ W via split-bf16 MFMA (hi*hi + hi*lo + lo*hi), h split in-kernel.
// Writes WhPack bf16 [B][jt=64][f=256][j'=32], s1/s2 (fp32 dots with a), and
// per-batch encoded atomicMax of s2 (for the k3 softmax bound).
// ---------------------------------------------------------------------------
__global__ __launch_bounds__(512, 2) void k1_mfma(const float* __restrict__ h,
                                                  const unsigned short* __restrict__ Bhi_g,
                                                  const unsigned short* __restrict__ Blo_g,
                                                  const float* __restrict__ a_g,
                                                  unsigned short* __restrict__ WhPack,
                                                  float* __restrict__ s1,
                                                  float* __restrict__ s2,
                                                  unsigned int* __restrict__ s2maxEnc) {
  __shared__ unsigned short Ah[64 * 264], Al[64 * 264];  // 33 KB each
  __shared__ unsigned short Bh[2][8192], Bl[2][8192];    // 16 KB per buffer
  __shared__ float s1red[64], s2red[64];
  const int t = threadIdx.x;
  const long r0 = (long)blockIdx.x * 64;
  const int wave = t >> 6, lane = t & 63;

  if (t < 64) { s1red[t] = 0.f; s2red[t] = 0.f; }

#pragma unroll
  for (int rep = 0; rep < 2; rep++) {
    const int off = wave * 1024 + rep * 512;
    gld16(Bhi_g + off + lane * 8, &Bh[0][off]);
    gld16(Blo_g + off + lane * 8, &Bl[0][off]);
  }

#pragma unroll
  for (int q = 0; q < 8; q++) {
    int idx = q * 512 + t;
    int row = idx >> 6, c4 = idx & 63;
    float4 x = *(const float4*)(h + (r0 + row) * 256 + c4 * 4);
    float xs[4] = {x.x, x.y, x.z, x.w};
    unsigned short hs[4], ls[4];
#pragma unroll
    for (int qq = 0; qq < 4; qq++) {
      hs[qq] = f2bf(xs[qq]);
      ls[qq] = f2bf(xs[qq] - bf2f(hs[qq]));
    }
    *(ushort4*)&Ah[row * 264 + c4 * 4] = (ushort4){hs[0], hs[1], hs[2], hs[3]};
    *(ushort4*)&Al[row * 264 + c4 * 4] = (ushort4){ls[0], ls[1], ls[2], ls[3]};
  }
  __syncthreads();

  const int wm = wave >> 2, wn = wave & 3;
  const int lhi = lane >> 4, llo = lane & 15;

  floatx4 acc[2][4];
#pragma unroll
  for (int mt = 0; mt < 2; mt++)
#pragma unroll
    for (int nt = 0; nt < 4; nt++) acc[mt][nt] = (floatx4){0.f, 0.f, 0.f, 0.f};

  for (int ks = 0; ks < 8; ks++) {
    const int cur = ks & 1, nxt = cur ^ 1, ksn = (ks + 1) & 7;
#pragma unroll
    for (int rep = 0; rep < 2; rep++) {
      const int off = wave * 1024 + rep * 512;
      gld16(Bhi_g + ksn * 8192 + off + lane * 8, &Bh[nxt][off]);
      gld16(Blo_g + ksn * 8192 + off + lane * 8, &Bl[nxt][off]);
    }

    const int k0 = ks * 32;
    bhalf8 ah[2], al[2], bh[4], bl[4];
#pragma unroll
    for (int mt = 0; mt < 2; mt++) {
      int ro = (wm * 32 + mt * 16 + llo) * 264 + k0 + lhi * 8;
      ah[mt] = *(const bhalf8*)&Ah[ro];
      al[mt] = *(const bhalf8*)&Al[ro];
    }
#pragma unroll
    for (int nt = 0; nt < 4; nt++) {
      int ro = (wn * 64 + nt * 16 + llo) * 32 + lhi * 8;
      bh[nt] = *(const bhalf8*)&Bh[cur][ro];
      bl[nt] = *(const bhalf8*)&Bl[cur][ro];
    }
#pragma unroll
    for (int mt = 0; mt < 2; mt++)
#pragma unroll
      for (int nt = 0; nt < 4; nt++) {
        acc[mt][nt] = __builtin_amdgcn_mfma_f32_16x16x32_bf16(ah[mt], bh[nt], acc[mt][nt], 0, 0, 0);
        acc[mt][nt] = __builtin_amdgcn_mfma_f32_16x16x32_bf16(ah[mt], bl[nt], acc[mt][nt], 0, 0, 0);
        acc[mt][nt] = __builtin_amdgcn_mfma_f32_16x16x32_bf16(al[mt], bh[nt], acc[mt][nt], 0, 0, 0);
      }
    __syncthreads();
  }

  float a1v[4], a2v[4];
#pragma unroll
  for (int nt = 0; nt < 4; nt++) {
    int f = wn * 64 + nt * 16 + llo;
    a1v[nt] = a_g[f];
    a2v[nt] = a_g[256 + f];
  }

  const int b = (int)(r0 >> 11);
  const int jt_base = (int)((r0 & 2047) >> 5);

#pragma unroll
  for (int mt = 0; mt < 2; mt++) {
    float p1[4], p2[4];
#pragma unroll
    for (int reg = 0; reg < 4; reg++) {
      p1[reg] = acc[mt][0][reg] * a1v[0] + acc[mt][1][reg] * a1v[1] +
                acc[mt][2][reg] * a1v[2] + acc[mt][3][reg] * a1v[3];
      p2[reg] = acc[mt][0][reg] * a2v[0] + acc[mt][1][reg] * a2v[1] +
                acc[mt][2][reg] * a2v[2] + acc[mt][3][reg] * a2v[3];
    }
#pragma unroll
    for (int off = 1; off < 16; off <<= 1) {
#pragma unroll
      for (int reg = 0; reg < 4; reg++) {
        p1[reg] += __shfl_xor(p1[reg], off);
        p2[reg] += __shfl_xor(p2[reg], off);
      }
    }
    if (llo == 0) {
#pragma unroll
      for (int reg = 0; reg < 4; reg++) {
        int il = wm * 32 + mt * 16 + lhi * 4 + reg;
        atomicAdd(&s1red[il], p1[reg]);
        atomicAdd(&s2red[il], p2[reg]);
      }
    }
#pragma unroll
    for (int nt = 0; nt < 4; nt++) {
      int f = wn * 64 + nt * 16 + llo;
      int jt = jt_base + wm;
      ushort4 pk = (ushort4){f2bf(acc[mt][nt][0]), f2bf(acc[mt][nt][1]),
                             f2bf(acc[mt][nt][2]), f2bf(acc[mt][nt][3])};
      *(ushort4*)&WhPack[((long)((b * 64 + jt) * 256 + f)) * 32 + mt * 16 + lhi * 4] = pk;
    }
  }

  __syncthreads();
  if (t < 64) {
    s1[r0 + t] = s1red[t];
    s2[r0 + t] = s2red[t];
    // per-batch max(s2): 64-lane reduce + one encoded atomicMax per block
    float v = s2red[t];
#pragma unroll
    for (int o = 32; o; o >>= 1) v = fmaxf(v, __shfl_xor(v, o));
    if (t == 0) {
      unsigned int u = __float_as_uint(v);
      unsigned int key = (u & 0x80000000u) ? ~u : (u | 0x80000000u);
      atomicMax(s2maxEnc + b, key);
    }
  }
}

// ---------------------------------------------------------------------------
// K3 v7 (LDS-shared P, 1x exp): out = elu(softmax(mask(leaky(s1+s2)))@Wh).
// Round-5 lesson: VALUBusy 54% = the 4x-redundant per-wave P recompute. Now
// each block (32 rows x 256 f, 4 waves) computes P ONCE: 256 threads x 4 exps
// per jt -> double-buffered LDS tile P[2][32][36] (pad->2-way banks = free).
// One raw lgkm-only s_barrier per jt (B-frags stay in REGISTERS; nothing
// vmcnt-drained -> no round-0 barrier stall). B loads issue at iteration top;
// ~150 cyc of P-compute covers their L1/L2 latency. mask/s2 prefetched one
// tile ahead (5 regs). Wave (rg,fg) = 16 rows x 128 f, 8 B-frags, 8 MFMA/jt.
// grid 512 x 256 thr, 2 blocks/CU; XCD-affine b = lin&7. LDS ~4.9 KB.
// ---------------------------------------------------------------------------
__global__ __launch_bounds__(256, 2) void k3_attn(const unsigned short* __restrict__ WhPack,
                                                  const unsigned int* __restrict__ mask32,
                                                  const float* __restrict__ s1g,
                                                  const float* __restrict__ s2g,
                                                  const unsigned int* __restrict__ s2maxEnc,
                                                  float* __restrict__ out) {
  const int t = threadIdx.x;
  const int lin = blockIdx.x;
  const int b = lin & 7;  // XCD-affine: round-robin dispatch -> XCD = lin%8
  const int ig = lin >> 3;
  const int i0 = ig * 32;
  const long gr0 = (long)b * 2048 + i0;

  const int wave = t >> 6, lane = t & 63;
  const int rg = wave >> 1, fg = wave & 1;
  const int llo = lane & 15, lhi = lane >> 4;
  const int prow = t >> 3;        // P row this thread computes (0..31)
  const int jq = (t & 7) * 4;     // P j-local base (4 per thread)

  __shared__ unsigned short P[2][32][36];  // 4.5 KB, pad 36 -> <=2-way banks
  __shared__ float lvv[32];

  // per-P-thread row constants
  const float s1i = s1g[gr0 + prow];
  const unsigned int ek = s2maxEnc[b];
  const float s2max = (ek & 0x80000000u) ? __uint_as_float(ek & 0x7fffffffu)
                                         : __uint_as_float(~ek);
  const float xm = s1i + s2max;
  const float Mi = fmaxf(xm, ALPHA_LR * xm);

  const unsigned int* maskrow = mask32 + (gr0 + prow) * 64;  // [jt]
  const float* s2p = s2g + (long)b * 2048;                   // + jt*32 + jq
  const unsigned short* wb =
      WhPack + (long)b * 524288 + (long)((fg * 128 + llo) * 32 + lhi * 8);

  float lsum = 0.f;

  // ---- prologue: P tile 0 -> P[0]; prefetch mask/s2 for tile 1 ----
  {
    unsigned int m = maskrow[0] >> jq;
    float4 s2v = *(const float4*)(s2p + jq);
    float xs[4] = {s2v.x, s2v.y, s2v.z, s2v.w};
    unsigned int pk[2];
    float e[4];
#pragma unroll
    for (int q = 0; q < 4; q++) {
      float x = s1i + xs[q];
      float lk = fmaxf(x, ALPHA_LR * x);
      float ee = __expf(lk - Mi);
      ee = (m >> q) & 1u ? ee : 0.f;
      lsum += ee;
      e[q] = ee;
    }
    asm("v_cvt_pk_bf16_f32 %0, %1, %2" : "=v"(pk[0]) : "v"(e[0]), "v"(e[1]));
    asm("v_cvt_pk_bf16_f32 %0, %1, %2" : "=v"(pk[1]) : "v"(e[2]), "v"(e[3]));
    *(uint2*)&P[0][prow][jq] = (uint2){pk[0], pk[1]};
  }
  unsigned int cm = maskrow[1];
  float4 cs2 = *(const float4*)(s2p + 32 + jq);
  asm volatile("s_waitcnt lgkmcnt(0)\n\ts_barrier" ::: "memory");

  floatx4 acc[8];
#pragma unroll
  for (int nt = 0; nt < 8; nt++) acc[nt] = (floatx4){0.f, 0.f, 0.f, 0.f};

#pragma unroll 2
  for (int jt = 0; jt < 64; jt++) {
    const int cur = jt & 1, nxt = cur ^ 1;

    // ---- issue: B-frags for CURRENT jt + mask/s2 for jt+2 ----
    bhalf8 bF[8];
#pragma unroll
    for (int nt = 0; nt < 8; nt++)
      bF[nt] = *(const bhalf8*)(wb + (long)jt * 8192 + nt * 512);
    const int jp = (jt < 62) ? jt + 2 : 63;
    unsigned int nm = maskrow[jp];
    float4 ns2 = *(const float4*)(s2p + jp * 32 + jq);
    __builtin_amdgcn_sched_barrier(0);  // loads may not sink below

    // ---- P tile jt+1 -> P[nxt] (1x redundancy) ----
    if (jt < 63) {
      unsigned int m = cm >> jq;
      float xs[4] = {cs2.x, cs2.y, cs2.z, cs2.w};
      unsigned int pk[2];
      float e[4];
#pragma unroll
      for (int q = 0; q < 4; q++) {
        float x = s1i + xs[q];
        float lk = fmaxf(x, ALPHA_LR * x);
        float ee = __expf(lk - Mi);
        ee = (m >> q) & 1u ? ee : 0.f;
        lsum += ee;
        e[q] = ee;
      }
      asm("v_cvt_pk_bf16_f32 %0, %1, %2" : "=v"(pk[0]) : "v"(e[0]), "v"(e[1]));
      asm("v_cvt_pk_bf16_f32 %0, %1, %2" : "=v"(pk[1]) : "v"(e[2]), "v"(e[3]));
      *(uint2*)&P[nxt][prow][jq] = (uint2){pk[0], pk[1]};
    }
    cm = nm; cs2 = ns2;

    // ---- A-frag from P[cur] + 8 MFMA ----
    bhalf8 af = *(const bhalf8*)&P[cur][rg * 16 + llo][lhi * 8];
#pragma unroll
    for (int nt = 0; nt < 8; nt++)
      acc[nt] = __builtin_amdgcn_mfma_f32_16x16x32_bf16(af, bF[nt], acc[nt], 0, 0, 0);

    // ---- raw barrier: drain LDS ops only (global loads stay in flight) ----
    asm volatile("s_waitcnt lgkmcnt(0)\n\ts_barrier" ::: "memory");
  }

  // denominator: 8 threads (contiguous lanes) share row prow
  lsum += __shfl_xor(lsum, 1);
  lsum += __shfl_xor(lsum, 2);
  lsum += __shfl_xor(lsum, 4);
  if ((lane & 7) == 0) lvv[prow] = lsum;
  __syncthreads();

  // epilogue: normalize, ELU, store. C/D: row = lhi*4+reg, col = llo
#pragma unroll
  for (int reg = 0; reg < 4; reg++) {
    const int rloc = rg * 16 + lhi * 4 + reg;
    const float iv = 1.f / fmaxf(lvv[rloc], 1e-35f);
    const long orow = (gr0 + rloc) * 256 + fg * 128 + llo;
#pragma unroll
    for (int nt = 0; nt < 8; nt++) {
      float v = acc[nt][reg] * iv;
      v = v > 0.f ? v : expm1f(v);
      out[orow + nt * 16] = v;
    }
  }
}

// ---------------------------------------------------------------------------
extern "C" void kernel_launch(void* const* d_in, const int* in_sizes, int n_in,
                              void* d_out, int out_size, void* d_ws, size_t ws_size,
                              hipStream_t stream) {
  const float* h = (const float*)d_in[0];
  const int* adj = (const int*)d_in[1];
  const float* W = (const float*)d_in[2];
  const float* a = (const float*)d_in[3];
  float* out = (float*)d_out;

  char* ws = (char*)d_ws;
  unsigned short* WhPack = (unsigned short*)ws;            //  8,388,608 B
  unsigned short* WThi = (unsigned short*)(ws + 8388608);  //    131,072 B
  unsigned short* WTlo = (unsigned short*)(ws + 8519680);  //    131,072 B
  float* s1 = (float*)(ws + 8650752);                      //     65,536 B
  float* s2 = (float*)(ws + 8716288);                      //     65,536 B
  unsigned int* s2maxEnc = (unsigned int*)(ws + 8781824);  //         32 B
  unsigned long long* adjMask = (unsigned long long*)(ws + 8912896);  // 4,194,304 B

  hipLaunchKernelGGL(k0w_split, dim3(16, 16), dim3(16, 16), 0, stream, W, WThi, WTlo, s2maxEnc);
  hipLaunchKernelGGL(k1_mfma, dim3(256), dim3(512), 0, stream, h, WThi, WTlo, a,
                     WhPack, s1, s2, s2maxEnc);
  hipLaunchKernelGGL(k2_pack, dim3(2048), dim3(256), 0, stream, adj, adjMask);
  hipLaunchKernelGGL(k3_attn, dim3(512), dim3(256), 0, stream, WhPack,
                     (const unsigned int*)adjMask, s1, s2, s2maxEnc, out);
}

// Round 7
// 264.920 us; speedup vs baseline: 1.1214x; 1.1141x over previous
//
#include <hip/hip_runtime.h>

typedef __attribute__((ext_vector_type(8))) short bhalf8;
typedef __attribute__((ext_vector_type(4))) float floatx4;

#define ALPHA_LR 0.2f

__device__ __forceinline__ unsigned short f2bf(float f) {
  union { float f; unsigned int u; } v; v.f = f;
  unsigned int r = v.u + 0x7fffu + ((v.u >> 16) & 1u);
  return (unsigned short)(r >> 16);
}
__device__ __forceinline__ float bf2f(unsigned short u) {
  union { unsigned int u; float f; } v; v.u = ((unsigned int)u) << 16;
  return v.f;
}
// async global->LDS, 16B per lane; LDS dest is wave-uniform base + lane*16
__device__ __forceinline__ void gld16(const void* g, void* l) {
  __builtin_amdgcn_global_load_lds((const __attribute__((address_space(1))) unsigned int*)g,
                                   (__attribute__((address_space(3))) unsigned int*)l,
                                   16, 0, 0);
}

// ---------------------------------------------------------------------------
// k0w: W [k][n] fp32 -> WT_hi/WT_lo bf16, k-tiled layout [ks=8][n=256][k'=32].
// Also re-initializes s2maxEnc[8] (ws is re-poisoned before every call).
// ---------------------------------------------------------------------------
__global__ void k0w_split(const float* __restrict__ W,
                          unsigned short* __restrict__ WThi,
                          unsigned short* __restrict__ WTlo,
                          unsigned int* __restrict__ s2maxEnc) {
  __shared__ float s[16][17];
  const int tx = threadIdx.x, ty = threadIdx.y;
  if (blockIdx.x == 0 && blockIdx.y == 0 && ty == 0 && tx < 8) s2maxEnc[tx] = 0u;
  const int n0 = blockIdx.x * 16, k0 = blockIdx.y * 16;
  s[ty][tx] = W[(k0 + ty) * 256 + n0 + tx];
  __syncthreads();
  float v = s[tx][ty];  // = W[k0+tx][n0+ty]
  const int k = k0 + tx, n = n0 + ty;
  unsigned short hi = f2bf(v);
  unsigned short lo = f2bf(v - bf2f(hi));
  const int idx = (k >> 5) * 8192 + n * 32 + (k & 31);
  WThi[idx] = hi;
  WTlo[idx] = lo;
}

// ---------------------------------------------------------------------------
// k2_pack: adj int32 0/1 (134 MB) -> bitmask (4 MB). Wave reads 64 consecutive
// ints (256 B coalesced), __ballot(v>0) -> uint64, lane 0 writes. HBM-floor
// ~22 us. Viewed as uint32: mask32[row*64 + jt] = bits j=jt*32..+31.
// ---------------------------------------------------------------------------
__global__ __launch_bounds__(256) void k2_pack(const int* __restrict__ adj,
                                               unsigned long long* __restrict__ mask) {
  const int wave = threadIdx.x >> 6, lane = threadIdx.x & 63;
  const long wid = (long)blockIdx.x * 4 + wave;  // 0..8191
  const long u0 = wid * 64;                      // first uint64 this wave packs
  const int* base = adj + u0 * 64 + lane;
#pragma unroll
  for (int it = 0; it < 64; it += 4) {
    int v0 = base[(it + 0) * 64];
    int v1 = base[(it + 1) * 64];
    int v2 = base[(it + 2) * 64];
    int v3 = base[(it + 3) * 64];
    unsigned long long m0 = __ballot(v0 > 0);
    unsigned long long m1 = __ballot(v1 > 0);
    unsigned long long m2 = __ballot(v2 > 0);
    unsigned long long m3 = __ballot(v3 > 0);
    if (lane == 0) {
      mask[u0 + it + 0] = m0;
      mask[u0 + it + 1] = m1;
      mask[u0 + it + 2] = m2;
      mask[u0 + it + 3] = m3;
    }
  }
}

// ---------------------------------------------------------------------------
// k1: Wh = h @ W via split-bf16 MFMA (hi*hi + hi*lo + lo*hi), h split in-kernel.
// Writes WhPack bf16 [B][jt=64][f=256][j'=32], s1/s2 (fp32 dots with a), and
// per-batch encoded atomicMax of s2 (for the k3 softmax bound).
// ---------------------------------------------------------------------------
__global__ __launch_bounds__(512, 2) void k1_mfma(const float* __restrict__ h,
                                                  const unsigned short* __restrict__ Bhi_g,
                                                  const unsigned short* __restrict__ Blo_g,
                                                  const float* __restrict__ a_g,
                                                  unsigned short* __restrict__ WhPack,
                                                  float* __restrict__ s1,
                                                  float* __restrict__ s2,
                                                  unsigned int* __restrict__ s2maxEnc) {
  __shared__ unsigned short Ah[64 * 264], Al[64 * 264];  // 33 KB each
  __shared__ unsigned short Bh[2][8192], Bl[2][8192];    // 16 KB per buffer
  __shared__ float s1red[64], s2red[64];
  const int t = threadIdx.x;
  const long r0 = (long)blockIdx.x * 64;
  const int wave = t >> 6, lane = t & 63;

  if (t < 64) { s1red[t] = 0.f; s2red[t] = 0.f; }

#pragma unroll
  for (int rep = 0; rep < 2; rep++) {
    const int off = wave * 1024 + rep * 512;
    gld16(Bhi_g + off + lane * 8, &Bh[0][off]);
    gld16(Blo_g + off + lane * 8, &Bl[0][off]);
  }

#pragma unroll
  for (int q = 0; q < 8; q++) {
    int idx = q * 512 + t;
    int row = idx >> 6, c4 = idx & 63;
    float4 x = *(const float4*)(h + (r0 + row) * 256 + c4 * 4);
    float xs[4] = {x.x, x.y, x.z, x.w};
    unsigned short hs[4], ls[4];
#pragma unroll
    for (int qq = 0; qq < 4; qq++) {
      hs[qq] = f2bf(xs[qq]);
      ls[qq] = f2bf(xs[qq] - bf2f(hs[qq]));
    }
    *(ushort4*)&Ah[row * 264 + c4 * 4] = (ushort4){hs[0], hs[1], hs[2], hs[3]};
    *(ushort4*)&Al[row * 264 + c4 * 4] = (ushort4){ls[0], ls[1], ls[2], ls[3]};
  }
  __syncthreads();

  const int wm = wave >> 2, wn = wave & 3;
  const int lhi = lane >> 4, llo = lane & 15;

  floatx4 acc[2][4];
#pragma unroll
  for (int mt = 0; mt < 2; mt++)
#pragma unroll
    for (int nt = 0; nt < 4; nt++) acc[mt][nt] = (floatx4){0.f, 0.f, 0.f, 0.f};

  for (int ks = 0; ks < 8; ks++) {
    const int cur = ks & 1, nxt = cur ^ 1, ksn = (ks + 1) & 7;
#pragma unroll
    for (int rep = 0; rep < 2; rep++) {
      const int off = wave * 1024 + rep * 512;
      gld16(Bhi_g + ksn * 8192 + off + lane * 8, &Bh[nxt][off]);
      gld16(Blo_g + ksn * 8192 + off + lane * 8, &Bl[nxt][off]);
    }

    const int k0 = ks * 32;
    bhalf8 ah[2], al[2], bh[4], bl[4];
#pragma unroll
    for (int mt = 0; mt < 2; mt++) {
      int ro = (wm * 32 + mt * 16 + llo) * 264 + k0 + lhi * 8;
      ah[mt] = *(const bhalf8*)&Ah[ro];
      al[mt] = *(const bhalf8*)&Al[ro];
    }
#pragma unroll
    for (int nt = 0; nt < 4; nt++) {
      int ro = (wn * 64 + nt * 16 + llo) * 32 + lhi * 8;
      bh[nt] = *(const bhalf8*)&Bh[cur][ro];
      bl[nt] = *(const bhalf8*)&Bl[cur][ro];
    }
#pragma unroll
    for (int mt = 0; mt < 2; mt++)
#pragma unroll
      for (int nt = 0; nt < 4; nt++) {
        acc[mt][nt] = __builtin_amdgcn_mfma_f32_16x16x32_bf16(ah[mt], bh[nt], acc[mt][nt], 0, 0, 0);
        acc[mt][nt] = __builtin_amdgcn_mfma_f32_16x16x32_bf16(ah[mt], bl[nt], acc[mt][nt], 0, 0, 0);
        acc[mt][nt] = __builtin_amdgcn_mfma_f32_16x16x32_bf16(al[mt], bh[nt], acc[mt][nt], 0, 0, 0);
      }
    __syncthreads();
  }

  float a1v[4], a2v[4];
#pragma unroll
  for (int nt = 0; nt < 4; nt++) {
    int f = wn * 64 + nt * 16 + llo;
    a1v[nt] = a_g[f];
    a2v[nt] = a_g[256 + f];
  }

  const int b = (int)(r0 >> 11);
  const int jt_base = (int)((r0 & 2047) >> 5);

#pragma unroll
  for (int mt = 0; mt < 2; mt++) {
    float p1[4], p2[4];
#pragma unroll
    for (int reg = 0; reg < 4; reg++) {
      p1[reg] = acc[mt][0][reg] * a1v[0] + acc[mt][1][reg] * a1v[1] +
                acc[mt][2][reg] * a1v[2] + acc[mt][3][reg] * a1v[3];
      p2[reg] = acc[mt][0][reg] * a2v[0] + acc[mt][1][reg] * a2v[1] +
                acc[mt][2][reg] * a2v[2] + acc[mt][3][reg] * a2v[3];
    }
#pragma unroll
    for (int off = 1; off < 16; off <<= 1) {
#pragma unroll
      for (int reg = 0; reg < 4; reg++) {
        p1[reg] += __shfl_xor(p1[reg], off);
        p2[reg] += __shfl_xor(p2[reg], off);
      }
    }
    if (llo == 0) {
#pragma unroll
      for (int reg = 0; reg < 4; reg++) {
        int il = wm * 32 + mt * 16 + lhi * 4 + reg;
        atomicAdd(&s1red[il], p1[reg]);
        atomicAdd(&s2red[il], p2[reg]);
      }
    }
#pragma unroll
    for (int nt = 0; nt < 4; nt++) {
      int f = wn * 64 + nt * 16 + llo;
      int jt = jt_base + wm;
      ushort4 pk = (ushort4){f2bf(acc[mt][nt][0]), f2bf(acc[mt][nt][1]),
                             f2bf(acc[mt][nt][2]), f2bf(acc[mt][nt][3])};
      *(ushort4*)&WhPack[((long)((b * 64 + jt) * 256 + f)) * 32 + mt * 16 + lhi * 4] = pk;
    }
  }

  __syncthreads();
  if (t < 64) {
    s1[r0 + t] = s1red[t];
    s2[r0 + t] = s2red[t];
    // per-batch max(s2): 64-lane reduce + one encoded atomicMax per block
    float v = s2red[t];
#pragma unroll
    for (int o = 32; o; o >>= 1) v = fmaxf(v, __shfl_xor(v, o));
    if (t == 0) {
      unsigned int u = __float_as_uint(v);
      unsigned int key = (u & 0x80000000u) ? ~u : (u | 0x80000000u);
      atomicMax(s2maxEnc + b, key);
    }
  }
}

// ---------------------------------------------------------------------------
// K3 v8 (m97-structure GEMM, P computed into LDS):
// C[64x256] per block = P @ Wh, BK=64 (2 jt) per step, 32 steps. Per step:
//   - gld16 async-stage next Wh K-tile (32 KB) into LDS[nxt], SOURCE-swizzled
//     (granule ^= (f>>1)&3) so swizzled ds_reads are bank-uniform (rule #21)
//   - compute next P K-tile (64x64) 1x-redundant: 8 exps/thread -> Pl[nxt]
//     (pad-72 rows: write & read bank-uniform)
//   - 16 MFMA/wave on LDS[cur] (mt2 x nt4 x kk2)
//   - __syncthreads (full drain: loads issued at step TOP, drain at END costs
//     ~0 -- unlike round-1 where loads had to span barriers)
// mask from 4MB bitmask (L2), prefetch depth 2; s2 staged once in LDS (8 KB).
// LDS 90.3 KB; grid 256 x 512 thr (1 block/CU); XCD-affine b = lin&7.
// ---------------------------------------------------------------------------
__global__ __launch_bounds__(512, 2) void k3_attn(const unsigned short* __restrict__ WhPack,
                                                  const unsigned int* __restrict__ mask32,
                                                  const float* __restrict__ s1g,
                                                  const float* __restrict__ s2g,
                                                  const unsigned int* __restrict__ s2maxEnc,
                                                  float* __restrict__ out) {
  const int t = threadIdx.x;
  const int lin = blockIdx.x;
  const int b = lin & 7;  // XCD-affine: round-robin dispatch -> XCD = lin%8
  const int ig = lin >> 3;
  const long gr0 = (long)b * 2048 + ig * 64;

  const int wave = t >> 6, lane = t & 63;
  const int rg = wave >> 2, fg = wave & 3;  // wave tile: 32 rows x 64 f
  const int llo = lane & 15, lhi = lane >> 4;

  __shared__ unsigned short WhL[2][16384];  // 64 KB: [kk jt][f 256][j' 32] swz
  __shared__ unsigned short Pl[2][64 * 72]; // 18 KB: [row 64][j 64 pad 72]
  __shared__ float s2l[2048];               // 8 KB
  __shared__ float lvv[64];

  // ---- P-compute role: row pr (0..63), j-octet pq (0..7) ----
  const int pr = t >> 3;
  const int pq = t & 7;
  const int q2 = pq >> 2;          // jt parity within K-step
  const int shq = (pq & 3) * 8;    // bit shift in mask dword

  const float s1i = s1g[gr0 + pr];
  const unsigned int ek = s2maxEnc[b];
  const float s2max = (ek & 0x80000000u) ? __uint_as_float(ek & 0x7fffffffu)
                                         : __uint_as_float(~ek);
  const float xm = s1i + s2max;
  const float Mi = fmaxf(xm, ALPHA_LR * xm);
  const unsigned int* mrow = mask32 + (gr0 + pr) * 64;

  // ---- gld16 source (inverse-swizzled): lane-constant part ----
  // LDS linear L = i*4096 + wave*512 + lane*8 (ushort) -> f,granule; source
  // granule = (lane&3) ^ ((lane>>3)&3) so LDS[f][g] = global[f][g ^ (f>>1)&3]
  const int gsrc8 = (((lane & 3) ^ ((lane >> 3) & 3))) * 8;
  const unsigned short* wsrcB =
      WhPack + (long)b * 524288 + wave * 512 + (lane >> 2) * 32 + gsrc8;

  // ---- ds_read lane-constant offsets ----
  const int boff = fg * 2048 + llo * 32 + (lhi ^ ((llo >> 1) & 3)) * 8;  // B
  const int aoff = (rg * 32 + llo) * 72 + lhi * 8;                       // A

  // ---- prologue ----
  // stage s2 (whole batch) into LDS
  *(float4*)&s2l[t * 4] = *(const float4*)(s2g + (long)b * 2048 + t * 4);
  // stage Wh K-tile 0 (jt 0,1) into WhL[0]
#pragma unroll
  for (int i = 0; i < 4; i++)
    gld16(wsrcB + i * 4096, &WhL[0][i * 4096 + wave * 512]);
  unsigned int m0 = mrow[q2];      // mask for P step 0
  __syncthreads();  // s2l ready; WhL[0] landed (vmcnt drain); m0 valid

  float lsum = 0.f;
  {  // P step 0 -> Pl[0]
    unsigned int mb = m0 >> shq;
    float4 sA = *(const float4*)&s2l[pq * 8];
    float4 sB = *(const float4*)&s2l[pq * 8 + 4];
    float xs[8] = {sA.x, sA.y, sA.z, sA.w, sB.x, sB.y, sB.z, sB.w};
    unsigned int pk[4];
    float e[8];
#pragma unroll
    for (int q = 0; q < 8; q++) {
      float x = s1i + xs[q];
      float lk = fmaxf(x, ALPHA_LR * x);
      float ee = __expf(lk - Mi);
      ee = (mb >> q) & 1u ? ee : 0.f;
      lsum += ee;
      e[q] = ee;
    }
#pragma unroll
    for (int q = 0; q < 4; q++)
      asm("v_cvt_pk_bf16_f32 %0, %1, %2" : "=v"(pk[q]) : "v"(e[2 * q]), "v"(e[2 * q + 1]));
    *(uint4*)&Pl[0][pr * 72 + pq * 8] = (uint4){pk[0], pk[1], pk[2], pk[3]};
  }
  unsigned int mC = mrow[2 + q2];  // mask for P step 1
  __syncthreads();  // Pl[0] visible

  floatx4 acc[2][4];
#pragma unroll
  for (int mt = 0; mt < 2; mt++)
#pragma unroll
    for (int nt = 0; nt < 4; nt++) acc[mt][nt] = (floatx4){0.f, 0.f, 0.f, 0.f};

#pragma unroll 2
  for (int step = 0; step < 32; step++) {
    const int cur = step & 1, nxt = cur ^ 1;

    // ---- issue: stage next Wh K-tile + prefetch mask (depth 2) ----
    if (step < 31) {
      const long jb = (long)(step + 1) * 16384;  // (step+1)*2 jt * 8192
#pragma unroll
      for (int i = 0; i < 4; i++)
        gld16(wsrcB + jb + i * 4096, &WhL[nxt][i * 4096 + wave * 512]);
    }
    unsigned int mN = mrow[(step < 30 ? (step + 2) * 2 : 62) + q2];
    __builtin_amdgcn_sched_barrier(0);

    // ---- compute P for step+1 -> Pl[nxt] ----
    if (step < 31) {
      unsigned int mb = mC >> shq;
      const int sbase = (step + 1) * 64 + pq * 8;
      float4 sA = *(const float4*)&s2l[sbase];
      float4 sB = *(const float4*)&s2l[sbase + 4];
      float xs[8] = {sA.x, sA.y, sA.z, sA.w, sB.x, sB.y, sB.z, sB.w};
      unsigned int pk[4];
      float e[8];
#pragma unroll
      for (int q = 0; q < 8; q++) {
        float x = s1i + xs[q];
        float lk = fmaxf(x, ALPHA_LR * x);
        float ee = __expf(lk - Mi);
        ee = (mb >> q) & 1u ? ee : 0.f;
        lsum += ee;
        e[q] = ee;
      }
#pragma unroll
      for (int q = 0; q < 4; q++)
        asm("v_cvt_pk_bf16_f32 %0, %1, %2" : "=v"(pk[q]) : "v"(e[2 * q]), "v"(e[2 * q + 1]));
      *(uint4*)&Pl[nxt][pr * 72 + pq * 8] = (uint4){pk[0], pk[1], pk[2], pk[3]};
    }
    mC = mN;

    // ---- MFMA on current buffers: kk2 x (mt2 x nt4) ----
#pragma unroll
    for (int kk = 0; kk < 2; kk++) {
      bhalf8 aF[2], bF[4];
#pragma unroll
      for (int mt = 0; mt < 2; mt++)
        aF[mt] = *(const bhalf8*)&Pl[cur][aoff + mt * 1152 + kk * 32];
#pragma unroll
      for (int nt = 0; nt < 4; nt++)
        bF[nt] = *(const bhalf8*)&WhL[cur][kk * 8192 + nt * 512 + boff];
#pragma unroll
      for (int mt = 0; mt < 2; mt++)
#pragma unroll
        for (int nt = 0; nt < 4; nt++)
          acc[mt][nt] = __builtin_amdgcn_mfma_f32_16x16x32_bf16(aF[mt], bF[nt], acc[mt][nt], 0, 0, 0);
    }

    __syncthreads();  // full drain: staged loads were issued at step TOP
  }

  // ---- denominator: 8 consecutive lanes share row pr ----
  lsum += __shfl_xor(lsum, 1);
  lsum += __shfl_xor(lsum, 2);
  lsum += __shfl_xor(lsum, 4);
  if ((lane & 7) == 0) lvv[pr] = lsum;
  __syncthreads();

  // ---- epilogue: normalize, ELU, store. C/D: row = lhi*4+reg, col = llo ----
#pragma unroll
  for (int mt = 0; mt < 2; mt++) {
#pragma unroll
    for (int reg = 0; reg < 4; reg++) {
      const int rloc = rg * 32 + mt * 16 + lhi * 4 + reg;
      const float iv = 1.f / fmaxf(lvv[rloc], 1e-35f);
      const long orow = (gr0 + rloc) * 256 + fg * 64 + llo;
#pragma unroll
      for (int nt = 0; nt < 4; nt++) {
        float v = acc[mt][nt][reg] * iv;
        v = v > 0.f ? v : expm1f(v);
        out[orow + nt * 16] = v;
      }
    }
  }
}

// ---------------------------------------------------------------------------
extern "C" void kernel_launch(void* const* d_in, const int* in_sizes, int n_in,
                              void* d_out, int out_size, void* d_ws, size_t ws_size,
                              hipStream_t stream) {
  const float* h = (const float*)d_in[0];
  const int* adj = (const int*)d_in[1];
  const float* W = (const float*)d_in[2];
  const float* a = (const float*)d_in[3];
  float* out = (float*)d_out;

  char* ws = (char*)d_ws;
  unsigned short* WhPack = (unsigned short*)ws;            //  8,388,608 B
  unsigned short* WThi = (unsigned short*)(ws + 8388608);  //    131,072 B
  unsigned short* WTlo = (unsigned short*)(ws + 8519680);  //    131,072 B
  float* s1 = (float*)(ws + 8650752);                      //     65,536 B
  float* s2 = (float*)(ws + 8716288);                      //     65,536 B
  unsigned int* s2maxEnc = (unsigned int*)(ws + 8781824);  //         32 B
  unsigned long long* adjMask = (unsigned long long*)(ws + 8912896);  // 4,194,304 B

  hipLaunchKernelGGL(k0w_split, dim3(16, 16), dim3(16, 16), 0, stream, W, WThi, WTlo, s2maxEnc);
  hipLaunchKernelGGL(k1_mfma, dim3(256), dim3(512), 0, stream, h, WThi, WTlo, a,
                     WhPack, s1, s2, s2maxEnc);
  hipLaunchKernelGGL(k2_pack, dim3(2048), dim3(256), 0, stream, adj, adjMask);
  hipLaunchKernelGGL(k3_attn, dim3(256), dim3(512), 0, stream, WhPack,
                     (const unsigned int*)adjMask, s1, s2, s2maxEnc, out);
}

// Round 8
// 243.083 us; speedup vs baseline: 1.2221x; 1.0898x over previous
//
#include <hip/hip_runtime.h>

typedef __attribute__((ext_vector_type(8))) short bhalf8;
typedef __attribute__((ext_vector_type(4))) float floatx4;

#define ALPHA_LR 0.2f

__device__ __forceinline__ unsigned short f2bf(float f) {
  union { float f; unsigned int u; } v; v.f = f;
  unsigned int r = v.u + 0x7fffu + ((v.u >> 16) & 1u);
  return (unsigned short)(r >> 16);
}
__device__ __forceinline__ float bf2f(unsigned short u) {
  union { unsigned int u; float f; } v; v.u = ((unsigned int)u) << 16;
  return v.f;
}
// async global->LDS, 16B per lane; LDS dest is wave-uniform base + lane*16
__device__ __forceinline__ void gld16(const void* g, void* l) {
  __builtin_amdgcn_global_load_lds((const __attribute__((address_space(1))) unsigned int*)g,
                                   (__attribute__((address_space(3))) unsigned int*)l,
                                   16, 0, 0);
}

// ---------------------------------------------------------------------------
// k0w: W [k][n] fp32 -> WT_hi/WT_lo bf16, k-tiled layout [ks=8][n=256][k'=32].
// Also re-initializes s2maxEnc[8] (ws is re-poisoned before every call).
// ---------------------------------------------------------------------------
__global__ void k0w_split(const float* __restrict__ W,
                          unsigned short* __restrict__ WThi,
                          unsigned short* __restrict__ WTlo,
                          unsigned int* __restrict__ s2maxEnc) {
  __shared__ float s[16][17];
  const int tx = threadIdx.x, ty = threadIdx.y;
  if (blockIdx.x == 0 && blockIdx.y == 0 && ty == 0 && tx < 8) s2maxEnc[tx] = 0u;
  const int n0 = blockIdx.x * 16, k0 = blockIdx.y * 16;
  s[ty][tx] = W[(k0 + ty) * 256 + n0 + tx];
  __syncthreads();
  float v = s[tx][ty];  // = W[k0+tx][n0+ty]
  const int k = k0 + tx, n = n0 + ty;
  unsigned short hi = f2bf(v);
  unsigned short lo = f2bf(v - bf2f(hi));
  const int idx = (k >> 5) * 8192 + n * 32 + (k & 31);
  WThi[idx] = hi;
  WTlo[idx] = lo;
}

// ---------------------------------------------------------------------------
// k1: Wh = h @ W via split-bf16 MFMA (hi*hi + hi*lo + lo*hi), h split in-kernel.
// Writes WhPack bf16 [B][jt=64][f=256][j'=32], s1/s2 (fp32 dots with a), and
// per-batch encoded atomicMax of s2 (for the k3 softmax bound).
// ---------------------------------------------------------------------------
__global__ __launch_bounds__(512, 2) void k1_mfma(const float* __restrict__ h,
                                                  const unsigned short* __restrict__ Bhi_g,
                                                  const unsigned short* __restrict__ Blo_g,
                                                  const float* __restrict__ a_g,
                                                  unsigned short* __restrict__ WhPack,
                                                  float* __restrict__ s1,
                                                  float* __restrict__ s2,
                                                  unsigned int* __restrict__ s2maxEnc) {
  __shared__ unsigned short Ah[64 * 264], Al[64 * 264];  // 33 KB each
  __shared__ unsigned short Bh[2][8192], Bl[2][8192];    // 16 KB per buffer
  __shared__ float s1red[64], s2red[64];
  const int t = threadIdx.x;
  const long r0 = (long)blockIdx.x * 64;
  const int wave = t >> 6, lane = t & 63;

  if (t < 64) { s1red[t] = 0.f; s2red[t] = 0.f; }

#pragma unroll
  for (int rep = 0; rep < 2; rep++) {
    const int off = wave * 1024 + rep * 512;
    gld16(Bhi_g + off + lane * 8, &Bh[0][off]);
    gld16(Blo_g + off + lane * 8, &Bl[0][off]);
  }

#pragma unroll
  for (int q = 0; q < 8; q++) {
    int idx = q * 512 + t;
    int row = idx >> 6, c4 = idx & 63;
    float4 x = *(const float4*)(h + (r0 + row) * 256 + c4 * 4);
    float xs[4] = {x.x, x.y, x.z, x.w};
    unsigned short hs[4], ls[4];
#pragma unroll
    for (int qq = 0; qq < 4; qq++) {
      hs[qq] = f2bf(xs[qq]);
      ls[qq] = f2bf(xs[qq] - bf2f(hs[qq]));
    }
    *(ushort4*)&Ah[row * 264 + c4 * 4] = (ushort4){hs[0], hs[1], hs[2], hs[3]};
    *(ushort4*)&Al[row * 264 + c4 * 4] = (ushort4){ls[0], ls[1], ls[2], ls[3]};
  }
  __syncthreads();

  const int wm = wave >> 2, wn = wave & 3;
  const int lhi = lane >> 4, llo = lane & 15;

  floatx4 acc[2][4];
#pragma unroll
  for (int mt = 0; mt < 2; mt++)
#pragma unroll
    for (int nt = 0; nt < 4; nt++) acc[mt][nt] = (floatx4){0.f, 0.f, 0.f, 0.f};

  for (int ks = 0; ks < 8; ks++) {
    const int cur = ks & 1, nxt = cur ^ 1, ksn = (ks + 1) & 7;
#pragma unroll
    for (int rep = 0; rep < 2; rep++) {
      const int off = wave * 1024 + rep * 512;
      gld16(Bhi_g + ksn * 8192 + off + lane * 8, &Bh[nxt][off]);
      gld16(Blo_g + ksn * 8192 + off + lane * 8, &Bl[nxt][off]);
    }

    const int k0 = ks * 32;
    bhalf8 ah[2], al[2], bh[4], bl[4];
#pragma unroll
    for (int mt = 0; mt < 2; mt++) {
      int ro = (wm * 32 + mt * 16 + llo) * 264 + k0 + lhi * 8;
      ah[mt] = *(const bhalf8*)&Ah[ro];
      al[mt] = *(const bhalf8*)&Al[ro];
    }
#pragma unroll
    for (int nt = 0; nt < 4; nt++) {
      int ro = (wn * 64 + nt * 16 + llo) * 32 + lhi * 8;
      bh[nt] = *(const bhalf8*)&Bh[cur][ro];
      bl[nt] = *(const bhalf8*)&Bl[cur][ro];
    }
#pragma unroll
    for (int mt = 0; mt < 2; mt++)
#pragma unroll
      for (int nt = 0; nt < 4; nt++) {
        acc[mt][nt] = __builtin_amdgcn_mfma_f32_16x16x32_bf16(ah[mt], bh[nt], acc[mt][nt], 0, 0, 0);
        acc[mt][nt] = __builtin_amdgcn_mfma_f32_16x16x32_bf16(ah[mt], bl[nt], acc[mt][nt], 0, 0, 0);
        acc[mt][nt] = __builtin_amdgcn_mfma_f32_16x16x32_bf16(al[mt], bh[nt], acc[mt][nt], 0, 0, 0);
      }
    __syncthreads();
  }

  float a1v[4], a2v[4];
#pragma unroll
  for (int nt = 0; nt < 4; nt++) {
    int f = wn * 64 + nt * 16 + llo;
    a1v[nt] = a_g[f];
    a2v[nt] = a_g[256 + f];
  }

  const int b = (int)(r0 >> 11);
  const int jt_base = (int)((r0 & 2047) >> 5);

#pragma unroll
  for (int mt = 0; mt < 2; mt++) {
    float p1[4], p2[4];
#pragma unroll
    for (int reg = 0; reg < 4; reg++) {
      p1[reg] = acc[mt][0][reg] * a1v[0] + acc[mt][1][reg] * a1v[1] +
                acc[mt][2][reg] * a1v[2] + acc[mt][3][reg] * a1v[3];
      p2[reg] = acc[mt][0][reg] * a2v[0] + acc[mt][1][reg] * a2v[1] +
                acc[mt][2][reg] * a2v[2] + acc[mt][3][reg] * a2v[3];
    }
#pragma unroll
    for (int off = 1; off < 16; off <<= 1) {
#pragma unroll
      for (int reg = 0; reg < 4; reg++) {
        p1[reg] += __shfl_xor(p1[reg], off);
        p2[reg] += __shfl_xor(p2[reg], off);
      }
    }
    if (llo == 0) {
#pragma unroll
      for (int reg = 0; reg < 4; reg++) {
        int il = wm * 32 + mt * 16 + lhi * 4 + reg;
        atomicAdd(&s1red[il], p1[reg]);
        atomicAdd(&s2red[il], p2[reg]);
      }
    }
#pragma unroll
    for (int nt = 0; nt < 4; nt++) {
      int f = wn * 64 + nt * 16 + llo;
      int jt = jt_base + wm;
      ushort4 pk = (ushort4){f2bf(acc[mt][nt][0]), f2bf(acc[mt][nt][1]),
                             f2bf(acc[mt][nt][2]), f2bf(acc[mt][nt][3])};
      *(ushort4*)&WhPack[((long)((b * 64 + jt) * 256 + f)) * 32 + mt * 16 + lhi * 4] = pk;
    }
  }

  __syncthreads();
  if (t < 64) {
    s1[r0 + t] = s1red[t];
    s2[r0 + t] = s2red[t];
    // per-batch max(s2): 64-lane reduce + one encoded atomicMax per block
    float v = s2red[t];
#pragma unroll
    for (int o = 32; o; o >>= 1) v = fmaxf(v, __shfl_xor(v, o));
    if (t == 0) {
      unsigned int u = __float_as_uint(v);
      unsigned int key = (u & 0x80000000u) ? ~u : (u | 0x80000000u);
      atomicMax(s2maxEnc + b, key);
    }
  }
}

// ---------------------------------------------------------------------------
// K3 v9 (= v8 + direct adj stream, k2_pack DELETED):
// The bitmask had zero cross-block reuse (each mask row consumed by exactly
// one block) -> packing only moved the 134 MB adj read into a separate serial
// 21 us kernel. v8's step (~1.2 us) has an idle VMEM pipe, so k3 absorbs the
// stream: each P-thread reads its 8 adj ints (2 x int4; 8 threads = one 256-B
// contiguous row segment) register-prefetched ONE STEP ahead (slack ~3000 cyc
// >> 900 cyc HBM latency), pinned by the issue-block sched_barrier(0).
// Mask bits derived in-register. Rest identical to v8 (m97 structure):
//   - gld16 async-stage next Wh K-tile (32 KB) into LDS[nxt], source-swizzled
//   - compute next P K-tile (64x64) 1x-redundant -> Pl[nxt] (pad-72)
//   - 16 MFMA/wave (mt2 x nt4 x kk2); __syncthreads per step
// LDS 90.3 KB; grid 256 x 512 thr (1 block/CU); XCD-affine b = lin&7.
// ---------------------------------------------------------------------------
__global__ __launch_bounds__(512, 2) void k3_attn(const unsigned short* __restrict__ WhPack,
                                                  const int* __restrict__ adj,
                                                  const float* __restrict__ s1g,
                                                  const float* __restrict__ s2g,
                                                  const unsigned int* __restrict__ s2maxEnc,
                                                  float* __restrict__ out) {
  const int t = threadIdx.x;
  const int lin = blockIdx.x;
  const int b = lin & 7;  // XCD-affine: round-robin dispatch -> XCD = lin%8
  const int ig = lin >> 3;
  const long gr0 = (long)b * 2048 + ig * 64;

  const int wave = t >> 6, lane = t & 63;
  const int rg = wave >> 2, fg = wave & 3;  // wave tile: 32 rows x 64 f
  const int llo = lane & 15, lhi = lane >> 4;

  __shared__ unsigned short WhL[2][16384];  // 64 KB: [kk jt][f 256][j' 32] swz
  __shared__ unsigned short Pl[2][64 * 72]; // 18 KB: [row 64][j 64 pad 72]
  __shared__ float s2l[2048];               // 8 KB
  __shared__ float lvv[64];

  // ---- P-compute role: row pr (0..63), j-octet pq (0..7) ----
  const int pr = t >> 3;
  const int pq = t & 7;

  const float s1i = s1g[gr0 + pr];
  const unsigned int ek = s2maxEnc[b];
  const float s2max = (ek & 0x80000000u) ? __uint_as_float(ek & 0x7fffffffu)
                                         : __uint_as_float(~ek);
  const float xm = s1i + s2max;
  const float Mi = fmaxf(xm, ALPHA_LR * xm);
  // adj row segment for this thread: 8 ints at + (ptile)*64 + pq*8
  const int* arow = adj + (gr0 + pr) * 2048 + pq * 8;

  // ---- gld16 source (inverse-swizzled): lane-constant part ----
  // LDS linear L = i*4096 + wave*512 + lane*8 (ushort) -> f,granule; source
  // granule = (lane&3) ^ ((lane>>3)&3) so LDS[f][g] = global[f][g ^ (f>>1)&3]
  const int gsrc8 = (((lane & 3) ^ ((lane >> 3) & 3))) * 8;
  const unsigned short* wsrcB =
      WhPack + (long)b * 524288 + wave * 512 + (lane >> 2) * 32 + gsrc8;

  // ---- ds_read lane-constant offsets ----
  const int boff = fg * 2048 + llo * 32 + (lhi ^ ((llo >> 1) & 3)) * 8;  // B
  const int aoff = (rg * 32 + llo) * 72 + lhi * 8;                       // A

  // ---- prologue ----
  // stage s2 (whole batch) into LDS
  *(float4*)&s2l[t * 4] = *(const float4*)(s2g + (long)b * 2048 + t * 4);
  // stage Wh K-tile 0 (jt 0,1) into WhL[0]
#pragma unroll
  for (int i = 0; i < 4; i++)
    gld16(wsrcB + i * 4096, &WhL[0][i * 4096 + wave * 512]);
  // adj for P-tile 0 (used in prologue) and P-tile 1 (used at step 0)
  int4 a0A = *(const int4*)(arow);
  int4 a0B = *(const int4*)(arow + 4);
  int4 ajCA = *(const int4*)(arow + 64);
  int4 ajCB = *(const int4*)(arow + 68);
  __syncthreads();  // s2l ready; WhL[0] landed (vmcnt drain)

  float lsum = 0.f;
  {  // P tile 0 -> Pl[0]
    int am[8] = {a0A.x, a0A.y, a0A.z, a0A.w, a0B.x, a0B.y, a0B.z, a0B.w};
    float4 sA = *(const float4*)&s2l[pq * 8];
    float4 sB = *(const float4*)&s2l[pq * 8 + 4];
    float xs[8] = {sA.x, sA.y, sA.z, sA.w, sB.x, sB.y, sB.z, sB.w};
    unsigned int pk[4];
    float e[8];
#pragma unroll
    for (int q = 0; q < 8; q++) {
      float x = s1i + xs[q];
      float lk = fmaxf(x, ALPHA_LR * x);
      float ee = __expf(lk - Mi);
      ee = (am[q] > 0) ? ee : 0.f;
      lsum += ee;
      e[q] = ee;
    }
#pragma unroll
    for (int q = 0; q < 4; q++)
      asm("v_cvt_pk_bf16_f32 %0, %1, %2" : "=v"(pk[q]) : "v"(e[2 * q]), "v"(e[2 * q + 1]));
    *(uint4*)&Pl[0][pr * 72 + pq * 8] = (uint4){pk[0], pk[1], pk[2], pk[3]};
  }
  __syncthreads();  // Pl[0] visible

  floatx4 acc[2][4];
#pragma unroll
  for (int mt = 0; mt < 2; mt++)
#pragma unroll
    for (int nt = 0; nt < 4; nt++) acc[mt][nt] = (floatx4){0.f, 0.f, 0.f, 0.f};

#pragma unroll 2
  for (int step = 0; step < 32; step++) {
    const int cur = step & 1, nxt = cur ^ 1;

    // ---- issue: stage next Wh K-tile + adj for P-tile step+2 ----
    if (step < 31) {
      const long jb = (long)(step + 1) * 16384;  // (step+1)*2 jt * 8192
#pragma unroll
      for (int i = 0; i < 4; i++)
        gld16(wsrcB + jb + i * 4096, &WhL[nxt][i * 4096 + wave * 512]);
    }
    const int tp = (step < 30 ? step + 2 : 31) * 64;
    int4 ajNA = *(const int4*)(arow + tp);
    int4 ajNB = *(const int4*)(arow + tp + 4);
    __builtin_amdgcn_sched_barrier(0);

    // ---- compute P for tile step+1 -> Pl[nxt] ----
    if (step < 31) {
      int am[8] = {ajCA.x, ajCA.y, ajCA.z, ajCA.w, ajCB.x, ajCB.y, ajCB.z, ajCB.w};
      const int sbase = (step + 1) * 64 + pq * 8;
      float4 sA = *(const float4*)&s2l[sbase];
      float4 sB = *(const float4*)&s2l[sbase + 4];
      float xs[8] = {sA.x, sA.y, sA.z, sA.w, sB.x, sB.y, sB.z, sB.w};
      unsigned int pk[4];
      float e[8];
#pragma unroll
      for (int q = 0; q < 8; q++) {
        float x = s1i + xs[q];
        float lk = fmaxf(x, ALPHA_LR * x);
        float ee = __expf(lk - Mi);
        ee = (am[q] > 0) ? ee : 0.f;
        lsum += ee;
        e[q] = ee;
      }
#pragma unroll
      for (int q = 0; q < 4; q++)
        asm("v_cvt_pk_bf16_f32 %0, %1, %2" : "=v"(pk[q]) : "v"(e[2 * q]), "v"(e[2 * q + 1]));
      *(uint4*)&Pl[nxt][pr * 72 + pq * 8] = (uint4){pk[0], pk[1], pk[2], pk[3]};
    }
    ajCA = ajNA; ajCB = ajNB;

    // ---- MFMA on current buffers: kk2 x (mt2 x nt4) ----
#pragma unroll
    for (int kk = 0; kk < 2; kk++) {
      bhalf8 aF[2], bF[4];
#pragma unroll
      for (int mt = 0; mt < 2; mt++)
        aF[mt] = *(const bhalf8*)&Pl[cur][aoff + mt * 1152 + kk * 32];
#pragma unroll
      for (int nt = 0; nt < 4; nt++)
        bF[nt] = *(const bhalf8*)&WhL[cur][kk * 8192 + nt * 512 + boff];
#pragma unroll
      for (int mt = 0; mt < 2; mt++)
#pragma unroll
        for (int nt = 0; nt < 4; nt++)
          acc[mt][nt] = __builtin_amdgcn_mfma_f32_16x16x32_bf16(aF[mt], bF[nt], acc[mt][nt], 0, 0, 0);
    }

    __syncthreads();  // full drain: staged loads were issued at step TOP
  }

  // ---- denominator: 8 consecutive lanes share row pr ----
  lsum += __shfl_xor(lsum, 1);
  lsum += __shfl_xor(lsum, 2);
  lsum += __shfl_xor(lsum, 4);
  if ((lane & 7) == 0) lvv[pr] = lsum;
  __syncthreads();

  // ---- epilogue: normalize, ELU, store. C/D: row = lhi*4+reg, col = llo ----
#pragma unroll
  for (int mt = 0; mt < 2; mt++) {
#pragma unroll
    for (int reg = 0; reg < 4; reg++) {
      const int rloc = rg * 32 + mt * 16 + lhi * 4 + reg;
      const float iv = 1.f / fmaxf(lvv[rloc], 1e-35f);
      const long orow = (gr0 + rloc) * 256 + fg * 64 + llo;
#pragma unroll
      for (int nt = 0; nt < 4; nt++) {
        float v = acc[mt][nt][reg] * iv;
        v = v > 0.f ? v : expm1f(v);
        out[orow + nt * 16] = v;
      }
    }
  }
}

// ---------------------------------------------------------------------------
extern "C" void kernel_launch(void* const* d_in, const int* in_sizes, int n_in,
                              void* d_out, int out_size, void* d_ws, size_t ws_size,
                              hipStream_t stream) {
  const float* h = (const float*)d_in[0];
  const int* adj = (const int*)d_in[1];
  const float* W = (const float*)d_in[2];
  const float* a = (const float*)d_in[3];
  float* out = (float*)d_out;

  char* ws = (char*)d_ws;
  unsigned short* WhPack = (unsigned short*)ws;            //  8,388,608 B
  unsigned short* WThi = (unsigned short*)(ws + 8388608);  //    131,072 B
  unsigned short* WTlo = (unsigned short*)(ws + 8519680);  //    131,072 B
  float* s1 = (float*)(ws + 8650752);                      //     65,536 B
  float* s2 = (float*)(ws + 8716288);                      //     65,536 B
  unsigned int* s2maxEnc = (unsigned int*)(ws + 8781824);  //         32 B

  hipLaunchKernelGGL(k0w_split, dim3(16, 16), dim3(16, 16), 0, stream, W, WThi, WTlo, s2maxEnc);
  hipLaunchKernelGGL(k1_mfma, dim3(256), dim3(512), 0, stream, h, WThi, WTlo, a,
                     WhPack, s1, s2, s2maxEnc);
  hipLaunchKernelGGL(k3_attn, dim3(256), dim3(512), 0, stream, WhPack, adj,
                     s1, s2, s2maxEnc, out);
}